// Round 1
// baseline (319.282 us; speedup 1.0000x reference)
//
#include <hip/hip_runtime.h>
#include <cmath>

#define NH 8
#define NP 4
#define HD 32
#define DD 256
#define NN 4096   // H*W = 64*64
#define BB 8
#define MROWS (BB*NN)  // 32768

// ---------------------------------------------------------------------------
// fp32 tiled GEMM: C[M,256] = A[M,256] @ Bw[256, ldb-cols slice] + bias
// fixed: M=32768, N=256, K=256, lda=ldc=256. 64x64 tile, BK=32, 4x4 microtile.
// ---------------------------------------------------------------------------
__global__ __launch_bounds__(256) void gemm_k256(
    const float* __restrict__ A,
    const float* __restrict__ Bw, int ldb,
    const float* __restrict__ bias,
    float* __restrict__ C)
{
  __shared__ float As[32][68];   // [k][m], pad 68 keeps float4 align (68*4=272=17*16)
  __shared__ float Bs[32][68];   // [k][n]
  const int t  = threadIdx.x;
  const int tx = t & 15, ty = t >> 4;
  const int m0 = blockIdx.y * 64;
  const int n0 = blockIdx.x * 64;

  float acc[4][4];
#pragma unroll
  for (int i = 0; i < 4; ++i)
#pragma unroll
    for (int j = 0; j < 4; ++j) acc[i][j] = 0.f;

  for (int k0 = 0; k0 < 256; k0 += 32) {
#pragma unroll
    for (int u = 0; u < 2; ++u) {
      int f = t + u * 256;           // 0..511
      // A tile: 64 rows x 32 k = 512 float4 (transpose into As[k][m])
      int arow = f >> 3, akq = f & 7;
      float4 av = *(const float4*)&A[(size_t)(m0 + arow) * 256 + k0 + akq * 4];
      As[akq * 4 + 0][arow] = av.x;
      As[akq * 4 + 1][arow] = av.y;
      As[akq * 4 + 2][arow] = av.z;
      As[akq * 4 + 3][arow] = av.w;
      // B tile: 32 k-rows x 64 cols = 512 float4 (direct)
      int brow = f >> 4, bnq = f & 15;
      float4 bv = *(const float4*)&Bw[(size_t)(k0 + brow) * ldb + n0 + bnq * 4];
      *(float4*)&Bs[brow][bnq * 4] = bv;
    }
    __syncthreads();
#pragma unroll
    for (int kk = 0; kk < 32; ++kk) {
      float4 av = *(const float4*)&As[kk][ty * 4];
      float4 bv = *(const float4*)&Bs[kk][tx * 4];
      acc[0][0] += av.x * bv.x; acc[0][1] += av.x * bv.y; acc[0][2] += av.x * bv.z; acc[0][3] += av.x * bv.w;
      acc[1][0] += av.y * bv.x; acc[1][1] += av.y * bv.y; acc[1][2] += av.y * bv.z; acc[1][3] += av.y * bv.w;
      acc[2][0] += av.z * bv.x; acc[2][1] += av.z * bv.y; acc[2][2] += av.z * bv.z; acc[2][3] += av.z * bv.w;
      acc[3][0] += av.w * bv.x; acc[3][1] += av.w * bv.y; acc[3][2] += av.w * bv.z; acc[3][3] += av.w * bv.w;
    }
    __syncthreads();
  }

  float4 b4 = *(const float4*)&bias[n0 + tx * 4];
#pragma unroll
  for (int i = 0; i < 4; ++i) {
    float4 o;
    o.x = acc[i][0] + b4.x; o.y = acc[i][1] + b4.y;
    o.z = acc[i][2] + b4.z; o.w = acc[i][3] + b4.w;
    *(float4*)&C[(size_t)(m0 + ty * 4 + i) * 256 + n0 + tx * 4] = o;
  }
}

// ---------------------------------------------------------------------------
// offsets + attention logits GEMM + epilogue -> sampling table
// per (b,n,h): 16 entries of (spatial idx, combined weight = attn*bilinear*valid)
// block = 256 threads, 16 rows per block; grid = 2048
// ---------------------------------------------------------------------------
__global__ __launch_bounds__(256) void offatt_kernel(
    const float* __restrict__ x,
    const float* __restrict__ off_w,  const float* __restrict__ off_b,
    const float* __restrict__ attw_w, const float* __restrict__ attw_b,
    int* __restrict__ sidx, float* __restrict__ swgt)
{
  __shared__ float Xs[16][260];   // pad 260 -> 4 r-groups hit distinct banks
  __shared__ float Ws[64][96];    // combined [k][c]: c<64 off_w, else attw_w
  __shared__ float L[16][96];     // logits per row
  const int t = threadIdx.x;
  const int row0 = blockIdx.x * 16;

  // stage 16 rows of x (16*256 floats = 1024 float4)
  {
    const float4* src = (const float4*)(x + (size_t)row0 * 256);
#pragma unroll
    for (int u = 0; u < 4; ++u) {
      int f = t + u * 256;
      int r = f >> 6, kq = f & 63;
      float4 v4 = src[(size_t)r * 64 + kq];
      *(float4*)&Xs[r][kq * 4] = v4;   // (r*260+kq*4)*4 = r*1040+kq*16, 16B aligned
    }
  }

  const int r  = t >> 4;        // row 0..15 (16 lanes share a row)
  const int cg = t & 15;
  const int c0 = cg * 6;        // 16*6 = 96 cols
  float acc[6] = {0, 0, 0, 0, 0, 0};

  for (int k0 = 0; k0 < 256; k0 += 64) {
    for (int f = t; f < 64 * 96; f += 256) {
      int kk = f / 96, c = f % 96;
      Ws[kk][c] = (c < 64) ? off_w[(size_t)(k0 + kk) * 64 + c]
                           : attw_w[(size_t)(k0 + kk) * 32 + (c - 64)];
    }
    __syncthreads();
#pragma unroll 8
    for (int kk = 0; kk < 64; ++kk) {
      float xv = Xs[r][k0 + kk];
#pragma unroll
      for (int i = 0; i < 6; ++i) acc[i] += xv * Ws[kk][c0 + i];
    }
    __syncthreads();
  }

#pragma unroll
  for (int i = 0; i < 6; ++i) {
    int c = c0 + i;
    float b = (c < 64) ? off_b[c] : attw_b[c - 64];
    L[r][c] = acc[i] + b;
  }
  __syncthreads();

  if (t < 128) {
    int rr = t >> 3, h = t & 7;
    int row = row0 + rr;                 // global row in [0, B*N)
    int nl = row & (NN - 1);
    float refx = (float)(nl & 63);
    float refy = (float)(nl >> 6);
    // softmax over P=4 attention logits
    float a0 = L[rr][64 + h * 4 + 0];
    float a1 = L[rr][64 + h * 4 + 1];
    float a2 = L[rr][64 + h * 4 + 2];
    float a3 = L[rr][64 + h * 4 + 3];
    float mx = fmaxf(fmaxf(a0, a1), fmaxf(a2, a3));
    float e0 = expf(a0 - mx), e1 = expf(a1 - mx), e2 = expf(a2 - mx), e3 = expf(a3 - mx);
    float inv = 1.f / (e0 + e1 + e2 + e3);
    float at[4] = {e0 * inv, e1 * inv, e2 * inv, e3 * inv};

    size_t base = ((size_t)row * 8 + h) * 16;
#pragma unroll
    for (int p = 0; p < 4; ++p) {
      float gx = refx + 2.f * tanhf(L[rr][h * 8 + p * 2 + 0]);
      float gy = refy + 2.f * tanhf(L[rr][h * 8 + p * 2 + 1]);
      float x0f = floorf(gx), y0f = floorf(gy);
      int x0 = (int)x0f, y0 = (int)y0f;
      int x1 = x0 + 1,   y1 = y0 + 1;
      float wx1 = gx - x0f, wx0 = 1.f - wx1;
      float wy1 = gy - y0f, wy0 = 1.f - wy1;
      int cx0 = min(max(x0, 0), 63), cx1 = min(max(x1, 0), 63);
      int cy0 = min(max(y0, 0), 63), cy1 = min(max(y1, 0), 63);
      float vx0 = (x0 >= 0 && x0 < 64) ? 1.f : 0.f;
      float vx1 = (x1 >= 0 && x1 < 64) ? 1.f : 0.f;
      float vy0 = (y0 >= 0 && y0 < 64) ? 1.f : 0.f;
      float vy1 = (y1 >= 0 && y1 < 64) ? 1.f : 0.f;
      float ap = at[p];
      sidx[base + p * 4 + 0] = cy0 * 64 + cx0; swgt[base + p * 4 + 0] = ap * wx0 * wy0 * vx0 * vy0;
      sidx[base + p * 4 + 1] = cy0 * 64 + cx1; swgt[base + p * 4 + 1] = ap * wx1 * wy0 * vx1 * vy0;
      sidx[base + p * 4 + 2] = cy1 * 64 + cx0; swgt[base + p * 4 + 2] = ap * wx0 * wy1 * vx0 * vy1;
      sidx[base + p * 4 + 3] = cy1 * 64 + cx1; swgt[base + p * 4 + 3] = ap * wx1 * wy1 * vx1 * vy1;
    }
  }
}

// ---------------------------------------------------------------------------
// sampler: y[b,n,h*32+c] = sum_j w[b,n,h,j] * v[b, idx[b,n,h,j], h*32+c]
// block = 256 threads = 8 n-rows x 32 channels; grid = B*nh*(N/8) = 32768
// ---------------------------------------------------------------------------
__global__ __launch_bounds__(256) void sample_kernel(
    const float* __restrict__ v,
    const int* __restrict__ sidx, const float* __restrict__ swgt,
    float* __restrict__ y)
{
  __shared__ int   Li[8][16];
  __shared__ float Lw[8][16];
  const int bid = blockIdx.x;
  const int ntile = bid & 511;
  const int h = (bid >> 9) & 7;
  const int b = bid >> 12;
  const int n0 = ntile * 8;
  const int t = threadIdx.x;

  if (t < 128) {
    int nn = t >> 4, j = t & 15;
    size_t g = (((size_t)b * NN + n0 + nn) * 8 + h) * 16 + j;
    Li[nn][j] = sidx[g];
    Lw[nn][j] = swgt[g];
  }
  __syncthreads();

  const int c = t & 31, nn = t >> 5;
  const float* vb = v + (size_t)b * NN * 256 + h * 32 + c;
  float acc = 0.f;
#pragma unroll
  for (int j = 0; j < 16; ++j) {
    int idx = Li[nn][j];
    float w = Lw[nn][j];
    acc += w * vb[(size_t)idx * 256];
  }
  y[((size_t)b * NN + n0 + nn) * 256 + h * 32 + c] = acc;
}

// ---------------------------------------------------------------------------
extern "C" void kernel_launch(void* const* d_in, const int* in_sizes, int n_in,
                              void* d_out, int out_size, void* d_ws, size_t ws_size,
                              hipStream_t stream) {
  const float* x      = (const float*)d_in[0];
  const float* qkv_w  = (const float*)d_in[1];
  const float* qkv_b  = (const float*)d_in[2];
  const float* off_w  = (const float*)d_in[3];
  const float* off_b  = (const float*)d_in[4];
  const float* attw_w = (const float*)d_in[5];
  const float* attw_b = (const float*)d_in[6];
  const float* proj_w = (const float*)d_in[7];
  const float* proj_b = (const float*)d_in[8];
  float* out = (float*)d_out;

  char* ws = (char*)d_ws;
  float* v    = (float*)(ws);                    // 33,554,432 B
  float* y    = (float*)(ws + 33554432);         // 33,554,432 B
  int*   sidx = (int*)  (ws + 67108864);         // 16,777,216 B
  float* swgt = (float*)(ws + 83886080);         // 16,777,216 B  (total 96 MiB)

  dim3 gg(4, 512);  // N/64 x M/64
  // v = x @ qkv_w[:, 512:768] + qkv_b[512:768]   (q,k unused by the reference output)
  gemm_k256<<<gg, 256, 0, stream>>>(x, qkv_w + 512, 768, qkv_b + 512, v);
  // sampling table (offsets -> bilinear corners x softmax attn)
  offatt_kernel<<<2048, 256, 0, stream>>>(x, off_w, off_b, attw_w, attw_b, sidx, swgt);
  // gather + weight
  sample_kernel<<<32768, 256, 0, stream>>>(v, sidx, swgt, y);
  // out = y @ proj_w + proj_b
  gemm_k256<<<gg, 256, 0, stream>>>(y, proj_w, 256, proj_b, out);
}

// Round 2
// 183.589 us; speedup vs baseline: 1.7391x; 1.7391x over previous
//
#include <hip/hip_runtime.h>
#include <hip/hip_bf16.h>
#include <cmath>

#define NN 4096    // H*W
#define MROWS 32768

typedef __attribute__((ext_vector_type(8))) short short8;
typedef __attribute__((ext_vector_type(4))) float f32x4;

// ---------------------------------------------------------------------------
// weight prep: transpose + bf16-convert so every GEMM operand is k-contiguous
// wvT[n][k] = qkv_w[k][512+n]; pjT[n][k] = proj_w[k][n];
// woT[c][k] = c<64 ? off_w[k][c] : attw_w[k][c-64]; bcat = concat(off_b,attw_b)
// ---------------------------------------------------------------------------
__global__ __launch_bounds__(256) void cvt_w(
    const float* __restrict__ qkv_w, const float* __restrict__ off_w,
    const float* __restrict__ attw_w, const float* __restrict__ proj_w,
    const float* __restrict__ off_b, const float* __restrict__ attw_b,
    __hip_bfloat16* __restrict__ wvT, __hip_bfloat16* __restrict__ pjT,
    __hip_bfloat16* __restrict__ woT, float* __restrict__ bcat)
{
  for (int i = blockIdx.x * 256 + threadIdx.x; i < 155744; i += 65536) {
    if (i < 65536) {
      int n = i >> 8, k = i & 255;
      wvT[i] = __float2bfloat16(qkv_w[k * 768 + 512 + n]);
    } else if (i < 131072) {
      int j = i - 65536; int n = j >> 8, k = j & 255;
      pjT[j] = __float2bfloat16(proj_w[k * 256 + n]);
    } else if (i < 155648) {
      int j = i - 131072; int c = j >> 8, k = j & 255;
      woT[j] = __float2bfloat16(c < 64 ? off_w[k * 64 + c] : attw_w[k * 32 + (c - 64)]);
    } else {
      int c = i - 155648;
      bcat[c] = c < 64 ? off_b[c] : attw_b[c - 64];
    }
  }
}

// x (fp32) -> xb (bf16), 4 elems/thread
__global__ __launch_bounds__(256) void cvt_x(const float* __restrict__ x,
                                             __hip_bfloat16* __restrict__ xb)
{
  size_t i = (size_t)blockIdx.x * 256 + threadIdx.x;   // 0..2097151
  float4 v = *(const float4*)(x + i * 4);
  __hip_bfloat16 o[4] = {__float2bfloat16(v.x), __float2bfloat16(v.y),
                         __float2bfloat16(v.z), __float2bfloat16(v.w)};
  *(uint2*)(xb + i * 4) = *(uint2*)o;
}

// ---------------------------------------------------------------------------
// bf16 MFMA GEMM: out[M,256] = A[M,256] @ BT^T + bias.  BT is [256 n][256 k].
// 128x128 tile, BK=32, 4 waves (2x2), each wave 64x64 via 4x4 MFMA subtiles.
// LDS rows padded to 40 bf16 (stride 20 words -> only free 2-way conflicts).
// ---------------------------------------------------------------------------
template <bool OUTBF>
__global__ __launch_bounds__(256) void gemm_mfma(
    const short* __restrict__ A, const short* __restrict__ BT,
    const float* __restrict__ bias,
    float* __restrict__ outf, __hip_bfloat16* __restrict__ outb)
{
  __shared__ short As[128 * 40];
  __shared__ short Bs[128 * 40];
  const int t = threadIdx.x;
  const int m0 = blockIdx.y * 128, n0 = blockIdx.x * 128;
  const int wave = t >> 6, lane = t & 63, q = lane >> 4, ln = lane & 15;
  const int wm = (wave & 1) * 64, wn = (wave >> 1) * 64;

  f32x4 acc[4][4] = {};

  for (int k0 = 0; k0 < 256; k0 += 32) {
#pragma unroll
    for (int u = 0; u < 2; ++u) {
      int c = t + u * 256;            // 512 chunks of 8 bf16
      int row = c >> 2, kq = c & 3;
      *(int4*)&As[row * 40 + kq * 8] =
          *(const int4*)&A[(size_t)(m0 + row) * 256 + k0 + kq * 8];
      *(int4*)&Bs[row * 40 + kq * 8] =
          *(const int4*)&BT[(size_t)(n0 + row) * 256 + k0 + kq * 8];
    }
    __syncthreads();
    short8 a[4], b[4];
#pragma unroll
    for (int i = 0; i < 4; ++i) a[i] = *(const short8*)&As[(wm + i * 16 + ln) * 40 + q * 8];
#pragma unroll
    for (int j = 0; j < 4; ++j) b[j] = *(const short8*)&Bs[(wn + j * 16 + ln) * 40 + q * 8];
#pragma unroll
    for (int i = 0; i < 4; ++i)
#pragma unroll
      for (int j = 0; j < 4; ++j)
        acc[i][j] = __builtin_amdgcn_mfma_f32_16x16x32_bf16(a[i], b[j], acc[i][j], 0, 0, 0);
    __syncthreads();
  }

#pragma unroll
  for (int j = 0; j < 4; ++j) {
    int col = n0 + wn + j * 16 + ln;
    float bv = bias[col];
#pragma unroll
    for (int i = 0; i < 4; ++i) {
      int rowb = m0 + wm + i * 16 + q * 4;
#pragma unroll
      for (int r = 0; r < 4; ++r) {
        float val = acc[i][j][r] + bv;
        if (OUTBF) outb[(size_t)(rowb + r) * 256 + col] = __float2bfloat16(val);
        else       outf[(size_t)(rowb + r) * 256 + col] = val;
      }
    }
  }
}

// ---------------------------------------------------------------------------
// offsets+attention: bf16 MFMA GEMM (M=64/block, N=96) -> logits in LDS ->
// tanh/softmax/bilinear epilogue -> sampling table (16 idx+wgt per (row,h))
// ---------------------------------------------------------------------------
__global__ __launch_bounds__(256) void offatt_mfma(
    const short* __restrict__ A,    // xb
    const short* __restrict__ WT,   // [96][256]
    const float* __restrict__ bcat, // [96]
    int* __restrict__ sidx, float* __restrict__ swgt)
{
  __shared__ short As[64 * 40];
  __shared__ short Bs[96 * 40];
  __shared__ float L[64][100];
  const int t = threadIdx.x;
  const int m0 = blockIdx.x * 64;
  const int wave = t >> 6, lane = t & 63, q = lane >> 4, ln = lane & 15;
  const int wm = (wave & 1) * 32, wn = (wave >> 1) * 48;

  f32x4 acc[2][3] = {};

  for (int k0 = 0; k0 < 256; k0 += 32) {
    {
      int row = t >> 2, kq = t & 3;   // 256 chunks = 64 rows x 4
      *(int4*)&As[row * 40 + kq * 8] =
          *(const int4*)&A[(size_t)(m0 + row) * 256 + k0 + kq * 8];
    }
    for (int c = t; c < 384; c += 256) {  // 96 rows x 4
      int row = c >> 2, kq = c & 3;
      *(int4*)&Bs[row * 40 + kq * 8] =
          *(const int4*)&WT[(size_t)row * 256 + k0 + kq * 8];
    }
    __syncthreads();
    short8 a[2], b[3];
#pragma unroll
    for (int i = 0; i < 2; ++i) a[i] = *(const short8*)&As[(wm + i * 16 + ln) * 40 + q * 8];
#pragma unroll
    for (int j = 0; j < 3; ++j) b[j] = *(const short8*)&Bs[(wn + j * 16 + ln) * 40 + q * 8];
#pragma unroll
    for (int i = 0; i < 2; ++i)
#pragma unroll
      for (int j = 0; j < 3; ++j)
        acc[i][j] = __builtin_amdgcn_mfma_f32_16x16x32_bf16(a[i], b[j], acc[i][j], 0, 0, 0);
    __syncthreads();
  }

#pragma unroll
  for (int j = 0; j < 3; ++j) {
    int col = wn + j * 16 + ln;
    float bv = bcat[col];
#pragma unroll
    for (int i = 0; i < 2; ++i)
#pragma unroll
      for (int r = 0; r < 4; ++r)
        L[wm + i * 16 + q * 4 + r][col] = acc[i][j][r] + bv;
  }
  __syncthreads();

#pragma unroll
  for (int it = 0; it < 2; ++it) {
    int idx = t + it * 256;          // 512 = 64 rows x 8 heads
    int rr = idx >> 3, h = idx & 7;
    int row = m0 + rr;
    int nl = row & (NN - 1);
    float refx = (float)(nl & 63);
    float refy = (float)(nl >> 6);

    float a0 = L[rr][64 + h * 4 + 0], a1 = L[rr][64 + h * 4 + 1];
    float a2 = L[rr][64 + h * 4 + 2], a3 = L[rr][64 + h * 4 + 3];
    float mx = fmaxf(fmaxf(a0, a1), fmaxf(a2, a3));
    float e0 = expf(a0 - mx), e1 = expf(a1 - mx), e2 = expf(a2 - mx), e3 = expf(a3 - mx);
    float inv = 1.f / (e0 + e1 + e2 + e3);
    float at[4] = {e0 * inv, e1 * inv, e2 * inv, e3 * inv};

    size_t base = ((size_t)row * 8 + h) * 16;
#pragma unroll
    for (int p = 0; p < 4; ++p) {
      float gx = refx + 2.f * tanhf(L[rr][h * 8 + p * 2 + 0]);
      float gy = refy + 2.f * tanhf(L[rr][h * 8 + p * 2 + 1]);
      float x0f = floorf(gx), y0f = floorf(gy);
      int x0 = (int)x0f, y0 = (int)y0f;
      int x1 = x0 + 1,   y1 = y0 + 1;
      float wx1 = gx - x0f, wx0 = 1.f - wx1;
      float wy1 = gy - y0f, wy0 = 1.f - wy1;
      int cx0 = min(max(x0, 0), 63), cx1 = min(max(x1, 0), 63);
      int cy0 = min(max(y0, 0), 63), cy1 = min(max(y1, 0), 63);
      float vx0 = (x0 >= 0 && x0 < 64) ? 1.f : 0.f;
      float vx1 = (x1 >= 0 && x1 < 64) ? 1.f : 0.f;
      float vy0 = (y0 >= 0 && y0 < 64) ? 1.f : 0.f;
      float vy1 = (y1 >= 0 && y1 < 64) ? 1.f : 0.f;
      float ap = at[p];
      sidx[base + p * 4 + 0] = cy0 * 64 + cx0; swgt[base + p * 4 + 0] = ap * wx0 * wy0 * vx0 * vy0;
      sidx[base + p * 4 + 1] = cy0 * 64 + cx1; swgt[base + p * 4 + 1] = ap * wx1 * wy0 * vx1 * vy0;
      sidx[base + p * 4 + 2] = cy1 * 64 + cx0; swgt[base + p * 4 + 2] = ap * wx0 * wy1 * vx0 * vy1;
      sidx[base + p * 4 + 3] = cy1 * 64 + cx1; swgt[base + p * 4 + 3] = ap * wx1 * wy1 * vx1 * vy1;
    }
  }
}

// ---------------------------------------------------------------------------
// sampler: y[b,n,h*32+c] = sum_16 w * v_bf16[b, idx, h*32+c]  -> y bf16
// ---------------------------------------------------------------------------
__global__ __launch_bounds__(256) void sample_kernel(
    const __hip_bfloat16* __restrict__ v,
    const int* __restrict__ sidx, const float* __restrict__ swgt,
    __hip_bfloat16* __restrict__ y)
{
  __shared__ int   Li[8][16];
  __shared__ float Lw[8][16];
  const int bid = blockIdx.x;
  const int ntile = bid & 511;
  const int h = (bid >> 9) & 7;
  const int b = bid >> 12;
  const int n0 = ntile * 8;
  const int t = threadIdx.x;

  if (t < 128) {
    int nn = t >> 4, j = t & 15;
    size_t g = (((size_t)b * NN + n0 + nn) * 8 + h) * 16 + j;
    Li[nn][j] = sidx[g];
    Lw[nn][j] = swgt[g];
  }
  __syncthreads();

  const int c = t & 31, nn = t >> 5;
  const __hip_bfloat16* vb = v + (size_t)b * NN * 256 + h * 32 + c;
  float acc = 0.f;
#pragma unroll
  for (int j = 0; j < 16; ++j) {
    int idx = Li[nn][j];
    float w = Lw[nn][j];
    acc += w * __bfloat162float(vb[(size_t)idx * 256]);
  }
  y[((size_t)b * NN + n0 + nn) * 256 + h * 32 + c] = __float2bfloat16(acc);
}

// ---------------------------------------------------------------------------
extern "C" void kernel_launch(void* const* d_in, const int* in_sizes, int n_in,
                              void* d_out, int out_size, void* d_ws, size_t ws_size,
                              hipStream_t stream) {
  const float* x      = (const float*)d_in[0];
  const float* qkv_w  = (const float*)d_in[1];
  const float* qkv_b  = (const float*)d_in[2];
  const float* off_w  = (const float*)d_in[3];
  const float* off_b  = (const float*)d_in[4];
  const float* attw_w = (const float*)d_in[5];
  const float* attw_b = (const float*)d_in[6];
  const float* proj_w = (const float*)d_in[7];
  const float* proj_b = (const float*)d_in[8];
  float* out = (float*)d_out;

  char* ws = (char*)d_ws;
  __hip_bfloat16* xb  = (__hip_bfloat16*)(ws);                 // 16 MiB
  __hip_bfloat16* vb  = (__hip_bfloat16*)(ws + 16777216);      // 16 MiB
  __hip_bfloat16* yb  = (__hip_bfloat16*)(ws + 33554432);      // 16 MiB
  int*   sidx         = (int*)  (ws + 50331648);               // 16 MiB
  float* swgt         = (float*)(ws + 67108864);               // 16 MiB
  __hip_bfloat16* wvT = (__hip_bfloat16*)(ws + 83886080);      // 128 KiB
  __hip_bfloat16* pjT = (__hip_bfloat16*)(ws + 84017152);      // 128 KiB
  __hip_bfloat16* woT = (__hip_bfloat16*)(ws + 84148224);      // 48 KiB
  float* bcat         = (float*)(ws + 84197376);               // 384 B

  cvt_w<<<256, 256, 0, stream>>>(qkv_w, off_w, attw_w, proj_w, off_b, attw_b,
                                 wvT, pjT, woT, bcat);
  cvt_x<<<8192, 256, 0, stream>>>(x, xb);

  dim3 gg(2, 256);  // N/128 x M/128
  gemm_mfma<true><<<gg, 256, 0, stream>>>((const short*)xb, (const short*)wvT,
                                          qkv_b + 512, nullptr, vb);
  offatt_mfma<<<512, 256, 0, stream>>>((const short*)xb, (const short*)woT,
                                       bcat, sidx, swgt);
  sample_kernel<<<32768, 256, 0, stream>>>(vb, sidx, swgt, yb);
  gemm_mfma<false><<<gg, 256, 0, stream>>>((const short*)yb, (const short*)pjT,
                                           proj_b, out, nullptr);
}

// Round 3
// 160.688 us; speedup vs baseline: 1.9870x; 1.1425x over previous
//
#include <hip/hip_runtime.h>
#include <hip/hip_bf16.h>
#include <cmath>

#define NN 4096    // H*W
typedef __attribute__((ext_vector_type(8))) short short8;
typedef __attribute__((ext_vector_type(4))) float f32x4;

__device__ __forceinline__ float bf2f(unsigned short u) {
  union { unsigned int i; float f; } c; c.i = ((unsigned int)u) << 16; return c.f;
}

// ---------------------------------------------------------------------------
// weight prep (transpose + bf16):
//   wcatT[c][k], c in [0,384): c<256 -> qkv_w[k][512+c] (v slice)
//                              c<320 -> off_w[k][c-256]; c<352 -> attw_w[k][c-320]
//                              else 0 (pad so the fused GEMM has uniform N=384)
//   pjT[c][k] = proj_w[k][c]
// ---------------------------------------------------------------------------
__global__ __launch_bounds__(256) void cvt_w(
    const float* __restrict__ qkv_w, const float* __restrict__ off_w,
    const float* __restrict__ attw_w, const float* __restrict__ proj_w,
    __hip_bfloat16* __restrict__ wcatT, __hip_bfloat16* __restrict__ pjT)
{
  for (int i = blockIdx.x * 256 + threadIdx.x; i < 98304 + 65536; i += 65536) {
    if (i < 98304) {
      int c = i >> 8, k = i & 255;
      float v;
      if (c < 256)      v = qkv_w[k * 768 + 512 + c];
      else if (c < 320) v = off_w[k * 64 + (c - 256)];
      else if (c < 352) v = attw_w[k * 32 + (c - 320)];
      else              v = 0.f;
      wcatT[i] = __float2bfloat16(v);
    } else {
      int j = i - 98304; int c = j >> 8, k = j & 255;
      pjT[j] = __float2bfloat16(proj_w[k * 256 + c]);
    }
  }
}

// ---------------------------------------------------------------------------
// fused v-GEMM + offset/attention GEMM + table epilogue.
// A = x (fp32, converted to bf16 during staging), BT = wcatT [384][256].
// 128x128 tiles, grid (3, 256). Blocks with n0<256 write v (bf16).
// Block n0==256 holds the 96 logit cols: writes logits to LDS (reusing the
// As/Bs space), then computes the compressed sampling table:
//   per (row,head): 16 x ushort idx (32B) then 16 x fp16 weight (32B) = 64B.
// ---------------------------------------------------------------------------
__global__ __launch_bounds__(256) void gemm_voff(
    const float* __restrict__ x,
    const __hip_bfloat16* __restrict__ wcatT,
    const float* __restrict__ vbias,          // qkv_b + 512
    const float* __restrict__ off_b, const float* __restrict__ attw_b,
    __hip_bfloat16* __restrict__ vb,
    unsigned int* __restrict__ table)
{
  __shared__ float smemf[12800];              // 51200 B
  short* As = (short*)smemf;                  // 128 rows * 40 shorts
  short* Bs = As + 128 * 40;
  float (*L)[100] = (float(*)[100])smemf;     // aliased AFTER the K loop

  const int t = threadIdx.x;
  const int m0 = blockIdx.y * 128, n0 = blockIdx.x * 128;
  const int wave = t >> 6, lane = t & 63, q = lane >> 4, ln = lane & 15;
  const int wm = (wave & 1) * 64, wn = (wave >> 1) * 64;

  f32x4 acc[4][4] = {};

  const int srow = t >> 1, skh = (t & 1) * 16;   // staging: row/col + k-half
  const float* apg = x + (size_t)(m0 + srow) * 256 + skh;
  const __hip_bfloat16* bpg = wcatT + (size_t)(n0 + srow) * 256 + skh;

  for (int k0 = 0; k0 < 256; k0 += 32) {
    // A: 128 rows x 32 k, fp32 -> bf16 on the fly
    float4 f0 = *(const float4*)(apg + k0);
    float4 f1 = *(const float4*)(apg + k0 + 4);
    float4 f2 = *(const float4*)(apg + k0 + 8);
    float4 f3 = *(const float4*)(apg + k0 + 12);
    alignas(16) __hip_bfloat16 cv[16] = {
      __float2bfloat16(f0.x), __float2bfloat16(f0.y), __float2bfloat16(f0.z), __float2bfloat16(f0.w),
      __float2bfloat16(f1.x), __float2bfloat16(f1.y), __float2bfloat16(f1.z), __float2bfloat16(f1.w),
      __float2bfloat16(f2.x), __float2bfloat16(f2.y), __float2bfloat16(f2.z), __float2bfloat16(f2.w),
      __float2bfloat16(f3.x), __float2bfloat16(f3.y), __float2bfloat16(f3.z), __float2bfloat16(f3.w)};
    *(int4*)&As[srow * 40 + skh]     = ((int4*)cv)[0];
    *(int4*)&As[srow * 40 + skh + 8] = ((int4*)cv)[1];
    // B: 128 cols x 32 k, already bf16
    *(int4*)&Bs[srow * 40 + skh]     = *(const int4*)(bpg + k0);
    *(int4*)&Bs[srow * 40 + skh + 8] = *(const int4*)(bpg + k0 + 8);
    __syncthreads();

    short8 a[4], b[4];
#pragma unroll
    for (int i = 0; i < 4; ++i) a[i] = *(const short8*)&As[(wm + i * 16 + ln) * 40 + q * 8];
#pragma unroll
    for (int j = 0; j < 4; ++j) b[j] = *(const short8*)&Bs[(wn + j * 16 + ln) * 40 + q * 8];
#pragma unroll
    for (int i = 0; i < 4; ++i)
#pragma unroll
      for (int j = 0; j < 4; ++j)
        acc[i][j] = __builtin_amdgcn_mfma_f32_16x16x32_bf16(a[i], b[j], acc[i][j], 0, 0, 0);
    __syncthreads();
  }

  if (n0 < 256) {
    // ---- v output path ----
#pragma unroll
    for (int j = 0; j < 4; ++j) {
      int col = n0 + wn + j * 16 + ln;
      float bv = vbias[col];
#pragma unroll
      for (int i = 0; i < 4; ++i) {
        int rowb = m0 + wm + i * 16 + q * 4;
#pragma unroll
        for (int r = 0; r < 4; ++r)
          vb[(size_t)(rowb + r) * 256 + col] = __float2bfloat16(acc[i][j][r] + bv);
      }
    }
  } else {
    // ---- logits -> sampling table path ----
#pragma unroll
    for (int j = 0; j < 4; ++j) {
      int col = wn + j * 16 + ln;
      if (col < 96) {
        float bv = (col < 64) ? off_b[col] : attw_b[col - 64];
#pragma unroll
        for (int i = 0; i < 4; ++i)
#pragma unroll
          for (int r = 0; r < 4; ++r)
            L[wm + i * 16 + q * 4 + r][col] = acc[i][j][r] + bv;
      }
    }
    __syncthreads();

#pragma unroll
    for (int it = 0; it < 4; ++it) {
      int pl = t + it * 256;            // 1024 = 128 rows x 8 heads
      int rr = pl >> 3, h = pl & 7;
      int row = m0 + rr;
      int nl = row & (NN - 1);
      float refx = (float)(nl & 63);
      float refy = (float)(nl >> 6);

      float a0 = L[rr][64 + h * 4 + 0], a1 = L[rr][64 + h * 4 + 1];
      float a2 = L[rr][64 + h * 4 + 2], a3 = L[rr][64 + h * 4 + 3];
      float mx = fmaxf(fmaxf(a0, a1), fmaxf(a2, a3));
      float e0 = expf(a0 - mx), e1 = expf(a1 - mx), e2 = expf(a2 - mx), e3 = expf(a3 - mx);
      float inv = 1.f / (e0 + e1 + e2 + e3);
      float at[4] = {e0 * inv, e1 * inv, e2 * inv, e3 * inv};

      alignas(16) unsigned short idxs[16];
      alignas(16) _Float16 wsv[16];
#pragma unroll
      for (int p = 0; p < 4; ++p) {
        float gx = refx + 2.f * tanhf(L[rr][h * 8 + p * 2 + 0]);
        float gy = refy + 2.f * tanhf(L[rr][h * 8 + p * 2 + 1]);
        float x0f = floorf(gx), y0f = floorf(gy);
        int x0 = (int)x0f, y0 = (int)y0f;
        int x1 = x0 + 1,   y1 = y0 + 1;
        float wx1 = gx - x0f, wx0 = 1.f - wx1;
        float wy1 = gy - y0f, wy0 = 1.f - wy1;
        int cx0 = min(max(x0, 0), 63), cx1 = min(max(x1, 0), 63);
        int cy0 = min(max(y0, 0), 63), cy1 = min(max(y1, 0), 63);
        float vx0 = (x0 >= 0) ? 1.f : 0.f;        // x0<=63 always (gx<=65 -> x0<=65; x0>63 -> wx0 side uses vx? guard fully)
        float vx1 = (x1 <= 63) ? 1.f : 0.f;
        float vy0 = (y0 >= 0) ? 1.f : 0.f;
        float vy1 = (y1 <= 63) ? 1.f : 0.f;
        // full validity (x0 can exceed 63 only if gx>63 -> then x0 in [63,65]; handle both ends)
        vx0 *= (x0 <= 63) ? 1.f : 0.f;
        vx1 *= (x1 >= 0) ? 1.f : 0.f;
        vy0 *= (y0 <= 63) ? 1.f : 0.f;
        vy1 *= (y1 >= 0) ? 1.f : 0.f;
        float ap = at[p];
        idxs[p * 4 + 0] = (unsigned short)(cy0 * 64 + cx0);
        idxs[p * 4 + 1] = (unsigned short)(cy0 * 64 + cx1);
        idxs[p * 4 + 2] = (unsigned short)(cy1 * 64 + cx0);
        idxs[p * 4 + 3] = (unsigned short)(cy1 * 64 + cx1);
        wsv[p * 4 + 0] = (_Float16)(ap * wx0 * wy0 * vx0 * vy0);
        wsv[p * 4 + 1] = (_Float16)(ap * wx1 * wy0 * vx1 * vy0);
        wsv[p * 4 + 2] = (_Float16)(ap * wx0 * wy1 * vx0 * vy1);
        wsv[p * 4 + 3] = (_Float16)(ap * wx1 * wy1 * vx1 * vy1);
      }
      uint4* dst = (uint4*)(table + (size_t)(row * 8 + h) * 16);
      dst[0] = *(uint4*)&idxs[0];
      dst[1] = *(uint4*)&idxs[8];
      dst[2] = *(uint4*)&wsv[0];
      dst[3] = *(uint4*)&wsv[8];
    }
  }
}

// ---------------------------------------------------------------------------
// sampler: thread = (pair, 8-channel group). 64 pairs/block, table staged in
// LDS, gathers are 16B dwordx4 from v. y written bf16.
// ---------------------------------------------------------------------------
__global__ __launch_bounds__(256) void sample_kernel(
    const __hip_bfloat16* __restrict__ v,
    const unsigned int* __restrict__ table,
    __hip_bfloat16* __restrict__ y)
{
  __shared__ uint4 Tab[256];                 // 64 pairs x 64 B
  const int t = threadIdx.x;
  const int p0 = blockIdx.x * 64;
  Tab[t] = *(const uint4*)(table + (size_t)p0 * 16 + t * 4);
  __syncthreads();

  const int g = t & 3, p = t >> 2;
  const int pg = p0 + p;
  const int h = pg & 7;
  const int row = pg >> 3;                   // [0, 32768)
  const int b = row >> 12;
  const unsigned short* ip = (const unsigned short*)&Tab[p * 4];
  const _Float16* wp = (const _Float16*)((const char*)&Tab[p * 4] + 32);
  const char* vbase = (const char*)(v + (size_t)b * NN * 256 + h * 32 + g * 8);

  float acc[8] = {};
#pragma unroll
  for (int j = 0; j < 16; ++j) {
    float w = (float)wp[j];
    int idx = ip[j];
    int4 pk = *(const int4*)(vbase + (size_t)idx * 512);
    const unsigned short* u = (const unsigned short*)&pk;
#pragma unroll
    for (int c = 0; c < 8; ++c) acc[c] += w * bf2f(u[c]);
  }
  alignas(16) __hip_bfloat16 o[8];
#pragma unroll
  for (int c = 0; c < 8; ++c) o[c] = __float2bfloat16(acc[c]);
  *(int4*)((char*)y + ((size_t)row * 256 + h * 32 + g * 8) * 2) = *(int4*)o;
}

// ---------------------------------------------------------------------------
// proj GEMM: out[M,256] = yb @ pjT^T + proj_b, fp32 out. Same 128x128 MFMA.
// ---------------------------------------------------------------------------
__global__ __launch_bounds__(256) void gemm_proj(
    const short* __restrict__ A, const short* __restrict__ BT,
    const float* __restrict__ bias, float* __restrict__ out)
{
  __shared__ short As[128 * 40];
  __shared__ short Bs[128 * 40];
  const int t = threadIdx.x;
  const int m0 = blockIdx.y * 128, n0 = blockIdx.x * 128;
  const int wave = t >> 6, lane = t & 63, q = lane >> 4, ln = lane & 15;
  const int wm = (wave & 1) * 64, wn = (wave >> 1) * 64;

  f32x4 acc[4][4] = {};

  for (int k0 = 0; k0 < 256; k0 += 32) {
#pragma unroll
    for (int u = 0; u < 2; ++u) {
      int c = t + u * 256;
      int row = c >> 2, kq = c & 3;
      *(int4*)&As[row * 40 + kq * 8] =
          *(const int4*)&A[(size_t)(m0 + row) * 256 + k0 + kq * 8];
      *(int4*)&Bs[row * 40 + kq * 8] =
          *(const int4*)&BT[(size_t)(n0 + row) * 256 + k0 + kq * 8];
    }
    __syncthreads();
    short8 a[4], b[4];
#pragma unroll
    for (int i = 0; i < 4; ++i) a[i] = *(const short8*)&As[(wm + i * 16 + ln) * 40 + q * 8];
#pragma unroll
    for (int j = 0; j < 4; ++j) b[j] = *(const short8*)&Bs[(wn + j * 16 + ln) * 40 + q * 8];
#pragma unroll
    for (int i = 0; i < 4; ++i)
#pragma unroll
      for (int j = 0; j < 4; ++j)
        acc[i][j] = __builtin_amdgcn_mfma_f32_16x16x32_bf16(a[i], b[j], acc[i][j], 0, 0, 0);
    __syncthreads();
  }

#pragma unroll
  for (int j = 0; j < 4; ++j) {
    int col = n0 + wn + j * 16 + ln;
    float bv = bias[col];
#pragma unroll
    for (int i = 0; i < 4; ++i) {
      int rowb = m0 + wm + i * 16 + q * 4;
#pragma unroll
      for (int r = 0; r < 4; ++r)
        out[(size_t)(rowb + r) * 256 + col] = acc[i][j][r] + bv;
    }
  }
}

// ---------------------------------------------------------------------------
extern "C" void kernel_launch(void* const* d_in, const int* in_sizes, int n_in,
                              void* d_out, int out_size, void* d_ws, size_t ws_size,
                              hipStream_t stream) {
  const float* x      = (const float*)d_in[0];
  const float* qkv_w  = (const float*)d_in[1];
  const float* qkv_b  = (const float*)d_in[2];
  const float* off_w  = (const float*)d_in[3];
  const float* off_b  = (const float*)d_in[4];
  const float* attw_w = (const float*)d_in[5];
  const float* attw_b = (const float*)d_in[6];
  const float* proj_w = (const float*)d_in[7];
  const float* proj_b = (const float*)d_in[8];
  float* out = (float*)d_out;

  char* ws = (char*)d_ws;
  __hip_bfloat16* vb    = (__hip_bfloat16*)(ws);                 // 16 MiB
  __hip_bfloat16* yb    = (__hip_bfloat16*)(ws + 16777216);      // 16 MiB
  unsigned int*   table = (unsigned int*)  (ws + 33554432);      // 16 MiB
  __hip_bfloat16* wcatT = (__hip_bfloat16*)(ws + 50331648);      // 192 KiB
  __hip_bfloat16* pjT   = (__hip_bfloat16*)(ws + 50528256);      // 128 KiB

  cvt_w<<<256, 256, 0, stream>>>(qkv_w, off_w, attw_w, proj_w, wcatT, pjT);

  dim3 g1(3, 256);
  gemm_voff<<<g1, 256, 0, stream>>>(x, wcatT, qkv_b + 512, off_b, attw_b, vb, table);

  sample_kernel<<<4096, 256, 0, stream>>>(vb, table, yb);

  dim3 g2(2, 256);
  gemm_proj<<<g2, 256, 0, stream>>>((const short*)yb, (const short*)pjT, proj_b, out);
}

// Round 5
// 152.565 us; speedup vs baseline: 2.0928x; 1.0532x over previous
//
#include <hip/hip_runtime.h>
#include <hip/hip_bf16.h>
#include <cmath>

#define NN 4096    // H*W
typedef __attribute__((ext_vector_type(8))) short short8;
typedef __attribute__((ext_vector_type(4))) float f32x4;

__device__ __forceinline__ float bf2f(unsigned short u) {
  union { unsigned int i; float f; } c; c.i = ((unsigned int)u) << 16; return c.f;
}

// ---------------------------------------------------------------------------
// weight prep, coalesced reads (c contiguous per k-row), scattered bf16 writes
//   wcatT[c][k] c<256: qkv_w[k][512+c]; c<320: off_w[k][c-256];
//               c<352: attw_w[k][c-320]; else 0
//   pjT[c][k] = proj_w[k][c]
// ---------------------------------------------------------------------------
__global__ __launch_bounds__(256) void cvt_w(
    const float* __restrict__ qkv_w, const float* __restrict__ off_w,
    const float* __restrict__ attw_w, const float* __restrict__ proj_w,
    __hip_bfloat16* __restrict__ wcatT, __hip_bfloat16* __restrict__ pjT)
{
  const int t = threadIdx.x;
  if (blockIdx.x < 256) {
    int k = blockIdx.x;
    wcatT[t * 256 + k] = __float2bfloat16(qkv_w[k * 768 + 512 + t]);
    if (t < 128) {
      int c2 = 256 + t;
      float v = 0.f;
      if (c2 < 320)      v = off_w[k * 64 + (c2 - 256)];
      else if (c2 < 352) v = attw_w[k * 32 + (c2 - 320)];
      wcatT[c2 * 256 + k] = __float2bfloat16(v);
    }
  } else {
    int k = blockIdx.x - 256;
    pjT[t * 256 + k] = __float2bfloat16(proj_w[k * 256 + t]);
  }
}

// ---------------------------------------------------------------------------
// fused v-GEMM + offset/attention logits + sampling-table epilogue.
// 512 threads (8 waves, 2x4), tile 128 rows x 384 cols, x read exactly once.
// cols 0..255 -> v (bf16); cols 256..351 -> logits -> table; 352..383 pad.
// table layout (pair-major, matches R2 sampler): entry pair = row*8+h,
//   16 ushort idx (32B) + 16 fp16 w (32B) = 64B.
// ---------------------------------------------------------------------------
__global__ __launch_bounds__(512) void gemm_voff(
    const float* __restrict__ x,
    const __hip_bfloat16* __restrict__ wcatT,
    const float* __restrict__ vbias,
    const float* __restrict__ off_b, const float* __restrict__ attw_b,
    __hip_bfloat16* __restrict__ vb,
    unsigned int* __restrict__ table)
{
  __shared__ float smemf[12800];              // 51200 B
  short* As = (short*)smemf;                  // 128 * 40 shorts = 10240 B
  short* Bs = As + 128 * 40;                  // 384 * 40 shorts = 30720 B
  float (*L)[100] = (float(*)[100])smemf;     // aliased AFTER the K loop

  const int t = threadIdx.x;
  const int m0 = blockIdx.x * 128;
  const int wave = t >> 6, lane = t & 63, q = lane >> 4, ln = lane & 15;
  const int wm = (wave & 1) * 64, wn = (wave >> 1) * 96;

  f32x4 acc[4][6] = {};

  const int arow = t >> 2, aseg = t & 3;          // A staging: 128 rows x 4 segs
  const float* apg = x + (size_t)(m0 + arow) * 256 + aseg * 8;

  for (int k0 = 0; k0 < 256; k0 += 32) {
    // A: 128x32 fp32 -> bf16
    float4 f0 = *(const float4*)(apg + k0);
    float4 f1 = *(const float4*)(apg + k0 + 4);
    alignas(16) __hip_bfloat16 cv[8] = {
      __float2bfloat16(f0.x), __float2bfloat16(f0.y), __float2bfloat16(f0.z), __float2bfloat16(f0.w),
      __float2bfloat16(f1.x), __float2bfloat16(f1.y), __float2bfloat16(f1.z), __float2bfloat16(f1.w)};
    *(int4*)&As[arow * 40 + aseg * 8] = *(int4*)cv;
    // B: 384x32 bf16, 1536 16B units / 512 thr = 3 each
#pragma unroll
    for (int i = 0; i < 3; ++i) {
      int u = t + i * 512;
      int brow = u >> 2, bseg = u & 3;
      *(int4*)&Bs[brow * 40 + bseg * 8] =
          *(const int4*)&wcatT[(size_t)brow * 256 + k0 + bseg * 8];
    }
    __syncthreads();
    short8 a[4], b[6];
#pragma unroll
    for (int i = 0; i < 4; ++i) a[i] = *(const short8*)&As[(wm + i * 16 + ln) * 40 + q * 8];
#pragma unroll
    for (int j = 0; j < 6; ++j) b[j] = *(const short8*)&Bs[(wn + j * 16 + ln) * 40 + q * 8];
#pragma unroll
    for (int i = 0; i < 4; ++i)
#pragma unroll
      for (int j = 0; j < 6; ++j)
        acc[i][j] = __builtin_amdgcn_mfma_f32_16x16x32_bf16(a[i], b[j], acc[i][j], 0, 0, 0);
    __syncthreads();
  }

  // v outputs + logits to LDS
#pragma unroll
  for (int j = 0; j < 6; ++j) {
    int col = wn + j * 16 + ln;
    if (col < 256) {
      float bv = vbias[col];
#pragma unroll
      for (int i = 0; i < 4; ++i) {
        int rowb = m0 + wm + i * 16 + q * 4;
#pragma unroll
        for (int r = 0; r < 4; ++r)
          vb[(size_t)(rowb + r) * 256 + col] = __float2bfloat16(acc[i][j][r] + bv);
      }
    } else if (col < 352) {
      int lc = col - 256;
      float bv = (lc < 64) ? off_b[lc] : attw_b[lc - 64];
#pragma unroll
      for (int i = 0; i < 4; ++i)
#pragma unroll
        for (int r = 0; r < 4; ++r)
          L[wm + i * 16 + q * 4 + r][lc] = acc[i][j][r] + bv;
    }
  }
  __syncthreads();

  // table epilogue: 1024 (row,head) pairs, 2 per thread
#pragma unroll
  for (int it = 0; it < 2; ++it) {
    int pl = t + it * 512;
    int rr = pl >> 3, h = pl & 7;
    int row = m0 + rr;
    int nl = row & (NN - 1);
    float refx = (float)(nl & 63);
    float refy = (float)(nl >> 6);

    float a0 = L[rr][64 + h * 4 + 0], a1 = L[rr][64 + h * 4 + 1];
    float a2 = L[rr][64 + h * 4 + 2], a3 = L[rr][64 + h * 4 + 3];
    float mx = fmaxf(fmaxf(a0, a1), fmaxf(a2, a3));
    float e0 = expf(a0 - mx), e1 = expf(a1 - mx), e2 = expf(a2 - mx), e3 = expf(a3 - mx);
    float inv = 1.f / (e0 + e1 + e2 + e3);
    float at[4] = {e0 * inv, e1 * inv, e2 * inv, e3 * inv};

    alignas(16) unsigned short idxs[16];
    alignas(16) _Float16 wsv[16];
#pragma unroll
    for (int p = 0; p < 4; ++p) {
      float gx = refx + 2.f * tanhf(L[rr][h * 8 + p * 2 + 0]);
      float gy = refy + 2.f * tanhf(L[rr][h * 8 + p * 2 + 1]);
      float x0f = floorf(gx), y0f = floorf(gy);
      int x0 = (int)x0f, y0 = (int)y0f;
      int x1 = x0 + 1,   y1 = y0 + 1;
      float wx1 = gx - x0f, wx0 = 1.f - wx1;
      float wy1 = gy - y0f, wy0 = 1.f - wy1;
      int cx0 = min(max(x0, 0), 63), cx1 = min(max(x1, 0), 63);
      int cy0 = min(max(y0, 0), 63), cy1 = min(max(y1, 0), 63);
      float vx0 = (x0 >= 0 && x0 <= 63) ? 1.f : 0.f;
      float vx1 = (x1 >= 0 && x1 <= 63) ? 1.f : 0.f;
      float vy0 = (y0 >= 0 && y0 <= 63) ? 1.f : 0.f;
      float vy1 = (y1 >= 0 && y1 <= 63) ? 1.f : 0.f;
      float ap = at[p];
      idxs[p * 4 + 0] = (unsigned short)(cy0 * 64 + cx0);
      idxs[p * 4 + 1] = (unsigned short)(cy0 * 64 + cx1);
      idxs[p * 4 + 2] = (unsigned short)(cy1 * 64 + cx0);
      idxs[p * 4 + 3] = (unsigned short)(cy1 * 64 + cx1);
      wsv[p * 4 + 0] = (_Float16)(ap * wx0 * wy0 * vx0 * vy0);
      wsv[p * 4 + 1] = (_Float16)(ap * wx1 * wy0 * vx1 * vy0);
      wsv[p * 4 + 2] = (_Float16)(ap * wx0 * wy1 * vx0 * vy1);
      wsv[p * 4 + 3] = (_Float16)(ap * wx1 * wy1 * vx1 * vy1);
    }
    uint4* dst = (uint4*)(table + ((size_t)row * 8 + h) * 16);  // pair-major (R2)
    dst[0] = *(uint4*)&idxs[0];
    dst[1] = *(uint4*)&idxs[8];
    dst[2] = *(uint4*)&wsv[0];
    dst[3] = *(uint4*)&wsv[8];
  }
}

// ---------------------------------------------------------------------------
// sampler (R2-proven): thread = (pair, 8-channel group). 64 pairs/block,
// table staged in LDS, gathers are 16B dwordx4 from v. y written bf16.
// ---------------------------------------------------------------------------
__global__ __launch_bounds__(256) void sample_kernel(
    const __hip_bfloat16* __restrict__ v,
    const unsigned int* __restrict__ table,
    __hip_bfloat16* __restrict__ y)
{
  __shared__ uint4 Tab[256];                 // 64 pairs x 64 B
  const int t = threadIdx.x;
  const int p0 = blockIdx.x * 64;
  Tab[t] = *(const uint4*)(table + (size_t)p0 * 16 + t * 4);
  __syncthreads();

  const int g = t & 3, p = t >> 2;
  const int pg = p0 + p;
  const int h = pg & 7;
  const int row = pg >> 3;                   // [0, 32768)
  const int b = row >> 12;
  const unsigned short* ip = (const unsigned short*)&Tab[p * 4];
  const _Float16* wp = (const _Float16*)((const char*)&Tab[p * 4] + 32);
  const char* vbase = (const char*)(v + (size_t)b * NN * 256 + h * 32 + g * 8);

  float acc[8] = {};
#pragma unroll
  for (int j = 0; j < 16; ++j) {
    float w = (float)wp[j];
    int idx = ip[j];
    int4 pk = *(const int4*)(vbase + (size_t)idx * 512);
    const unsigned short* u = (const unsigned short*)&pk;
#pragma unroll
    for (int c = 0; c < 8; ++c) acc[c] += w * bf2f(u[c]);
  }
  alignas(16) __hip_bfloat16 o[8];
#pragma unroll
  for (int c = 0; c < 8; ++c) o[c] = __float2bfloat16(acc[c]);
  *(int4*)((char*)y + ((size_t)row * 256 + h * 32 + g * 8) * 2) = *(int4*)o;
}

// ---------------------------------------------------------------------------
// proj GEMM (R2-proven): out[M,256] = yb @ pjT^T + proj_b, fp32 out.
// ---------------------------------------------------------------------------
__global__ __launch_bounds__(256) void gemm_proj(
    const short* __restrict__ A, const short* __restrict__ BT,
    const float* __restrict__ bias, float* __restrict__ out)
{
  __shared__ short As[128 * 40];
  __shared__ short Bs[128 * 40];
  const int t = threadIdx.x;
  const int m0 = blockIdx.y * 128, n0 = blockIdx.x * 128;
  const int wave = t >> 6, lane = t & 63, q = lane >> 4, ln = lane & 15;
  const int wm = (wave & 1) * 64, wn = (wave >> 1) * 64;

  f32x4 acc[4][4] = {};

  for (int k0 = 0; k0 < 256; k0 += 32) {
#pragma unroll
    for (int u = 0; u < 2; ++u) {
      int c = t + u * 256;
      int row = c >> 2, kq = c & 3;
      *(int4*)&As[row * 40 + kq * 8] =
          *(const int4*)&A[(size_t)(m0 + row) * 256 + k0 + kq * 8];
      *(int4*)&Bs[row * 40 + kq * 8] =
          *(const int4*)&BT[(size_t)(n0 + row) * 256 + k0 + kq * 8];
    }
    __syncthreads();
    short8 a[4], b[4];
#pragma unroll
    for (int i = 0; i < 4; ++i) a[i] = *(const short8*)&As[(wm + i * 16 + ln) * 40 + q * 8];
#pragma unroll
    for (int j = 0; j < 4; ++j) b[j] = *(const short8*)&Bs[(wn + j * 16 + ln) * 40 + q * 8];
#pragma unroll
    for (int i = 0; i < 4; ++i)
#pragma unroll
      for (int j = 0; j < 4; ++j)
        acc[i][j] = __builtin_amdgcn_mfma_f32_16x16x32_bf16(a[i], b[j], acc[i][j], 0, 0, 0);
    __syncthreads();
  }

#pragma unroll
  for (int j = 0; j < 4; ++j) {
    int col = n0 + wn + j * 16 + ln;
    float bv = bias[col];
#pragma unroll
    for (int i = 0; i < 4; ++i) {
      int rowb = m0 + wm + i * 16 + q * 4;
#pragma unroll
      for (int r = 0; r < 4; ++r)
        out[(size_t)(rowb + r) * 256 + col] = acc[i][j][r] + bv;
    }
  }
}

// ---------------------------------------------------------------------------
extern "C" void kernel_launch(void* const* d_in, const int* in_sizes, int n_in,
                              void* d_out, int out_size, void* d_ws, size_t ws_size,
                              hipStream_t stream) {
  const float* x      = (const float*)d_in[0];
  const float* qkv_w  = (const float*)d_in[1];
  const float* qkv_b  = (const float*)d_in[2];
  const float* off_w  = (const float*)d_in[3];
  const float* off_b  = (const float*)d_in[4];
  const float* attw_w = (const float*)d_in[5];
  const float* attw_b = (const float*)d_in[6];
  const float* proj_w = (const float*)d_in[7];
  const float* proj_b = (const float*)d_in[8];
  float* out = (float*)d_out;

  char* ws = (char*)d_ws;
  __hip_bfloat16* vb    = (__hip_bfloat16*)(ws);                 // 16 MiB
  __hip_bfloat16* yb    = (__hip_bfloat16*)(ws + 16777216);      // 16 MiB
  unsigned int*   table = (unsigned int*)  (ws + 33554432);      // 16 MiB
  __hip_bfloat16* wcatT = (__hip_bfloat16*)(ws + 50331648);      // 192 KiB
  __hip_bfloat16* pjT   = (__hip_bfloat16*)(ws + 50528256);      // 128 KiB

  cvt_w<<<512, 256, 0, stream>>>(qkv_w, off_w, attw_w, proj_w, wcatT, pjT);
  gemm_voff<<<256, 512, 0, stream>>>(x, wcatT, qkv_b + 512, off_b, attw_b, vb, table);
  sample_kernel<<<4096, 256, 0, stream>>>(vb, table, yb);
  dim3 g2(2, 256);
  gemm_proj<<<g2, 256, 0, stream>>>((const short*)yb, (const short*)pjT, proj_b, out);
}